// Round 1
// baseline (167.290 us; speedup 1.0000x reference)
//
#include <hip/hip_runtime.h>

#define BATCH 131072
#define NDIM 64

// ws layout (floats):
//   [0 .. 8191]    U1c: row j (j=0..63) = { 64 floats Re(U1[j,:]), 64 floats Im(U1[j,:]) }
//   [8192 .. 8245] A: 6 matrices of 3x3 (recon_k = (l^T A_k l)/(l^T l))

__device__ __forceinline__ float fast_tanh(float v) {
    float e = __expf(2.0f * v);
    return 1.0f - 2.0f / (e + 1.0f);
}

// ---------------------------------------------------------------------------
// prep: build circuit-1 unitary (64x64 complex, stored as 128x64 real) and
// circuit-2 collapsed quadratic forms A_k (6 x 3 x 3).
// Blocks 0..7: evolve 8 basis columns each for circuit 1.
// Block 8:     evolve 3 basis columns for circuit 2, reduce to A.
// ---------------------------------------------------------------------------
__global__ __launch_bounds__(256) void prep_kernel(const float* __restrict__ enc_w,
                                                   const float* __restrict__ dec_w,
                                                   float* __restrict__ ws) {
    __shared__ float gt[36][8];   // 36 gates x {u00r,u00i,u01r,u01i,u10r,u10i,u11r,u11i}
    __shared__ float Sr[64][8];
    __shared__ float Si[64][8];

    const int t = threadIdx.x;
    const int blk = blockIdx.x;

    // Gate table: U = RZ(tz) @ RX(tx)
    // em = exp(-i tz/2) = (ch, -sh); ep = (ch, sh); c = cos(tx/2), s = sin(tx/2)
    // u00 = em*c = (c*ch, -c*sh); u01 = -i*em*s = (-s*sh, -s*ch)
    // u10 = -i*ep*s = (s*sh, -s*ch); u11 = ep*c = (c*ch, c*sh)
    if (t < 36) {
        int circ = t / 18, rem = t % 18;
        const float* wsrc = circ ? dec_w : enc_w;
        float tx = wsrc[rem * 3 + 0];
        float tz = wsrc[rem * 3 + 1];
        float c = cosf(0.5f * tx), s = sinf(0.5f * tx);
        float ch = cosf(0.5f * tz), sh = sinf(0.5f * tz);
        gt[t][0] = c * ch;  gt[t][1] = -c * sh;
        gt[t][2] = -s * sh; gt[t][3] = -s * ch;
        gt[t][4] = s * sh;  gt[t][5] = -s * ch;
        gt[t][6] = c * ch;  gt[t][7] = c * sh;
    }

    const int gbase = (blk == 8) ? 18 : 0;
    const int cl = t & 7;     // local column 0..7
    const int pr = t >> 3;    // pair index 0..31

    // init columns: blocks 0..7 -> basis columns 8*blk+cl; block 8 -> e_0,e_1,e_2
    float* fSr = &Sr[0][0];
    float* fSi = &Si[0][0];
    for (int f = t; f < 512; f += 256) {
        int r = f >> 3, c = f & 7;
        float v;
        if (blk < 8) v = (r == 8 * blk + c) ? 1.0f : 0.0f;
        else         v = (r == c && c < 3) ? 1.0f : 0.0f;
        fSr[f] = v;
        fSi[f] = 0.0f;
    }

    for (int bb = 0; bb < 3; ++bb) {
        for (int w = 0; w < 6; ++w) {
            __syncthreads();
            int g = gbase + bb * 6 + w;
            int p = 5 - w;  // wire w acts on bit (5-w)
            float u00r = gt[g][0], u00i = gt[g][1], u01r = gt[g][2], u01i = gt[g][3];
            float u10r = gt[g][4], u10i = gt[g][5], u11r = gt[g][6], u11i = gt[g][7];
            int r0 = ((pr >> p) << (p + 1)) | (pr & ((1 << p) - 1));
            int r1 = r0 | (1 << p);
            float ar = Sr[r0][cl], ai = Si[r0][cl];
            float br = Sr[r1][cl], bi = Si[r1][cl];
            Sr[r0][cl] = u00r * ar - u00i * ai + u01r * br - u01i * bi;
            Si[r0][cl] = u00r * ai + u00i * ar + u01r * bi + u01i * br;
            Sr[r1][cl] = u10r * ar - u10i * ai + u11r * br - u11i * bi;
            Si[r1][cl] = u10r * ai + u10i * ar + u11r * bi + u11i * br;
        }
        __syncthreads();
        // CZ chain: row sign = (-1)^popcount(r & (r>>1))
        for (int f = t; f < 512; f += 256) {
            int r = f >> 3;
            if (__popc(r & (r >> 1)) & 1) {
                fSr[f] = -fSr[f];
                fSi[f] = -fSi[f];
            }
        }
    }
    __syncthreads();

    if (blk < 8) {
        for (int f = t; f < 512; f += 256) {
            int j = f >> 3, c = f & 7;
            ws[j * 128 + 8 * blk + c]      = Sr[j][c];
            ws[j * 128 + 64 + 8 * blk + c] = Si[j][c];
        }
    } else {
        // A_k[d][e] = sum_r s_k(r) * (Mr[r][d]Mr[r][e] + Mi[r][d]Mi[r][e])
        if (t < 54) {
            int k = t / 9, d = (t % 9) / 3, e = t % 3;
            float acc = 0.0f;
            for (int r = 0; r < 64; ++r) {
                float term = Sr[r][d] * Sr[r][e] + Si[r][d] * Si[r][e];
                acc += ((r >> (5 - k)) & 1) ? -term : term;
            }
            ws[8192 + t] = acc;
        }
    }
}

// ---------------------------------------------------------------------------
// main: one thread per batch element.
// ---------------------------------------------------------------------------
__global__ __launch_bounds__(256) void qae_main(const float* __restrict__ x,
                                                const float* __restrict__ Wp,
                                                const float* __restrict__ bp,
                                                const float* __restrict__ ws,
                                                float* __restrict__ out) {
    __shared__ float sU[8192];  // 32 KB: row j = 64 re + 64 im
    __shared__ float sW[512];   // row i: W[i][0..5], b[i], pad
    __shared__ float sA[56];

    const int t = threadIdx.x;

    {
        const float4* Ug = (const float4*)ws;
        float4* Us = (float4*)sU;
#pragma unroll
        for (int q = 0; q < 8; ++q) Us[t + 256 * q] = Ug[t + 256 * q];
        for (int f = t; f < 512; f += 256) {
            int i = f >> 3, c = f & 7;
            sW[f] = (c < 6) ? Wp[i * 6 + c] : ((c == 6) ? bp[i] : 0.0f);
        }
        if (t < 54) sA[t] = ws[8192 + t];
    }
    __syncthreads();

    const int b = blockIdx.x * 256 + t;  // grid exactly covers BATCH

    float xv[6];
#pragma unroll
    for (int d = 0; d < 6; ++d) xv[d] = x[b * 6 + d];

    // h = tanh(x W^T + b), S = ||h||^2
    float h[64];
    float S = 0.0f;
#pragma unroll
    for (int i = 0; i < 64; ++i) {
        float4 w0 = *(const float4*)&sW[i * 8];
        float4 w1 = *(const float4*)&sW[i * 8 + 4];
        float a = w1.z + w0.x * xv[0] + w0.y * xv[1] + w0.z * xv[2] +
                  w0.w * xv[3] + w1.x * xv[4] + w1.y * xv[5];
        float th = fast_tanh(a);
        h[i] = th;
        S += th * th;
    }
    float invS = __builtin_amdgcn_rcpf(S);

    // y = U1c h ; p_j = (yre^2 + yim^2)/S ; latent_k = sum_j s_k(j) p_j
    float l0 = 0.0f, l1 = 0.0f, l2 = 0.0f;
    for (int j = 0; j < 64; ++j) {
        const float4* rr = (const float4*)&sU[j * 128];
        float ar = 0.0f, ai = 0.0f;
#pragma unroll
        for (int q = 0; q < 16; ++q) {
            float4 u = rr[q];
            float4 v = rr[q + 16];
            ar += u.x * h[4 * q] + u.y * h[4 * q + 1] + u.z * h[4 * q + 2] + u.w * h[4 * q + 3];
            ai += v.x * h[4 * q] + v.y * h[4 * q + 1] + v.z * h[4 * q + 2] + v.w * h[4 * q + 3];
        }
        float p = ar * ar + ai * ai;
        l0 += (j & 32) ? -p : p;
        l1 += (j & 16) ? -p : p;
        l2 += (j & 8) ? -p : p;
    }
    l0 *= invS; l1 *= invS; l2 *= invS;

    out[(size_t)BATCH * 64 + (size_t)b * 3 + 0] = l0;
    out[(size_t)BATCH * 64 + (size_t)b * 3 + 1] = l1;
    out[(size_t)BATCH * 64 + (size_t)b * 3 + 2] = l2;

    // decoder circuit collapsed: recon_k = (l^T A_k l) / (l^T l)
    float r2 = l0 * l0 + l1 * l1 + l2 * l2;
    float invr2 = __builtin_amdgcn_rcpf(r2);
    float lv[3] = {l0, l1, l2};
    float rec[6];
#pragma unroll
    for (int k = 0; k < 6; ++k) {
        float acc = 0.0f;
#pragma unroll
        for (int d = 0; d < 3; ++d)
#pragma unroll
            for (int e = 0; e < 3; ++e) acc += sA[k * 9 + d * 3 + e] * lv[d] * lv[e];
        rec[k] = acc * invr2;
    }

    // reconstructed = tanh(rec W^T + b)
    float* ob = out + (size_t)b * 64;
#pragma unroll
    for (int i4 = 0; i4 < 16; ++i4) {
        float vals[4];
#pragma unroll
        for (int c = 0; c < 4; ++c) {
            int i = i4 * 4 + c;
            float4 w0 = *(const float4*)&sW[i * 8];
            float4 w1 = *(const float4*)&sW[i * 8 + 4];
            float a = w1.z + w0.x * rec[0] + w0.y * rec[1] + w0.z * rec[2] +
                      w0.w * rec[3] + w1.x * rec[4] + w1.y * rec[5];
            vals[c] = fast_tanh(a);
        }
        float4 o = {vals[0], vals[1], vals[2], vals[3]};
        *(float4*)&ob[i4 * 4] = o;
    }
}

extern "C" void kernel_launch(void* const* d_in, const int* in_sizes, int n_in,
                              void* d_out, int out_size, void* d_ws, size_t ws_size,
                              hipStream_t stream) {
    const float* x   = (const float*)d_in[0];
    const float* Wp  = (const float*)d_in[1];
    const float* bpv = (const float*)d_in[2];
    const float* enc = (const float*)d_in[3];
    const float* dec = (const float*)d_in[4];
    float* out = (float*)d_out;
    float* ws  = (float*)d_ws;

    prep_kernel<<<9, 256, 0, stream>>>(enc, dec, ws);
    qae_main<<<BATCH / 256, 256, 0, stream>>>(x, Wp, bpv, ws, out);
}

// Round 2
// 129.392 us; speedup vs baseline: 1.2929x; 1.2929x over previous
//
#include <hip/hip_runtime.h>

#define BATCH 131072

// ws layout (floats):
//  [0..53]     A: 6 matrices 3x3 (decoder collapsed: recon_k = (l^T A_k l)/(l^T l))
//  [64..99]    enc RX coeffs: gate g=bb*6+w -> ws[64+2g]=cos(tx/2), ws[65+2g]=sin(tx/2)
//  [128..511]  enc diag per block bb: ws[128+128*bb+2r]=Re D_r, +1=Im D_r
//              (D folds all 6 RZ phases of the block + the CZ-chain signs)

__device__ __forceinline__ float fast_tanh(float v) {
    float e = __expf(2.0f * v);
    return 1.0f - 2.0f / (e + 1.0f);
}

// ---------------------------------------------------------------------------
// prep: (single block) decoder collapsed quadratic forms + encoder gate params
// ---------------------------------------------------------------------------
__global__ __launch_bounds__(256) void prep_kernel(const float* __restrict__ enc_w,
                                                   const float* __restrict__ dec_w,
                                                   float* __restrict__ ws) {
    __shared__ float gt[18][8];
    __shared__ float Sr[64][8];
    __shared__ float Si[64][8];
    const int t = threadIdx.x;

    // decoder gate table: U = RZ(tz) @ RX(tx)
    if (t < 18) {
        float tx = dec_w[t * 3 + 0];
        float tz = dec_w[t * 3 + 1];
        float c = cosf(0.5f * tx), s = sinf(0.5f * tx);
        float ch = cosf(0.5f * tz), sh = sinf(0.5f * tz);
        gt[t][0] = c * ch;  gt[t][1] = -c * sh;
        gt[t][2] = -s * sh; gt[t][3] = -s * ch;
        gt[t][4] = s * sh;  gt[t][5] = -s * ch;
        gt[t][6] = c * ch;  gt[t][7] = c * sh;
    }

    const int cl = t & 7;
    const int pr = t >> 3;
    float* fSr = &Sr[0][0];
    float* fSi = &Si[0][0];
    for (int f = t; f < 512; f += 256) {
        int r = f >> 3, c = f & 7;
        fSr[f] = (r == c && c < 3) ? 1.0f : 0.0f;
        fSi[f] = 0.0f;
    }

    for (int bb = 0; bb < 3; ++bb) {
        for (int w = 0; w < 6; ++w) {
            __syncthreads();
            int g = bb * 6 + w;
            int p = 5 - w;
            float u00r = gt[g][0], u00i = gt[g][1], u01r = gt[g][2], u01i = gt[g][3];
            float u10r = gt[g][4], u10i = gt[g][5], u11r = gt[g][6], u11i = gt[g][7];
            int r0 = ((pr >> p) << (p + 1)) | (pr & ((1 << p) - 1));
            int r1 = r0 | (1 << p);
            float ar = Sr[r0][cl], ai = Si[r0][cl];
            float br = Sr[r1][cl], bi = Si[r1][cl];
            Sr[r0][cl] = u00r * ar - u00i * ai + u01r * br - u01i * bi;
            Si[r0][cl] = u00r * ai + u00i * ar + u01r * bi + u01i * br;
            Sr[r1][cl] = u10r * ar - u10i * ai + u11r * br - u11i * bi;
            Si[r1][cl] = u10r * ai + u10i * ar + u11r * bi + u11i * br;
        }
        __syncthreads();
        for (int f = t; f < 512; f += 256) {
            int r = f >> 3;
            if (__popc(r & (r >> 1)) & 1) {
                fSr[f] = -fSr[f];
                fSi[f] = -fSi[f];
            }
        }
    }
    __syncthreads();

    // A_k[d][e] = sum_r s_k(r) * (Mr[r][d]Mr[r][e] + Mi[r][d]Mi[r][e])
    if (t < 54) {
        int k = t / 9, d = (t % 9) / 3, e = t % 3;
        float acc = 0.0f;
        for (int r = 0; r < 64; ++r) {
            float term = Sr[r][d] * Sr[r][e] + Si[r][d] * Si[r][e];
            acc += ((r >> (5 - k)) & 1) ? -term : term;
        }
        ws[t] = acc;
    }

    // encoder RX coefficients
    if (t < 18) {
        float tx = enc_w[t * 3 + 0];
        ws[64 + 2 * t] = cosf(0.5f * tx);
        ws[65 + 2 * t] = sinf(0.5f * tx);
    }

    // encoder per-block diagonal (all RZ + CZ folded)
    if (t >= 64 && t < 256) {
        int idx = t - 64;            // 0..191
        int bb = idx >> 6, r = idx & 63;
        float phi = 0.0f;
        for (int k = 0; k < 6; ++k) {
            float tz = enc_w[(bb * 6 + k) * 3 + 1];
            // RZ(tz) = diag(e^{-i tz/2}, e^{+i tz/2}) acting on bit (5-k)
            phi += ((r >> (5 - k)) & 1) ? 0.5f * tz : -0.5f * tz;
        }
        float sgn = (__popc(r & (r >> 1)) & 1) ? -1.0f : 1.0f;
        ws[128 + bb * 128 + 2 * r] = sgn * cosf(phi);
        ws[129 + bb * 128 + 2 * r] = sgn * sinf(phi);
    }
}

// ---------------------------------------------------------------------------
// RX butterfly on wire with bit position P (all indices compile-time)
// RX: a' = c*a - i s*b ; b' = -i s*a + c*b
// ---------------------------------------------------------------------------
template <int P>
__device__ __forceinline__ void apply_rx(float* sr, float* si, float c, float s) {
#pragma unroll
    for (int m = 0; m < 32; ++m) {
        int lo = m & ((1 << P) - 1);
        int r0 = ((m >> P) << (P + 1)) | lo;
        int r1 = r0 | (1 << P);
        float ar = sr[r0], ai = si[r0], br = sr[r1], bi = si[r1];
        sr[r0] = c * ar + s * bi;
        si[r0] = c * ai - s * br;
        sr[r1] = c * br + s * ai;
        si[r1] = c * bi - s * ar;
    }
}

// ---------------------------------------------------------------------------
// main: one thread per batch element; circuit evolved in registers.
// ---------------------------------------------------------------------------
__global__ __launch_bounds__(256) void qae_main(const float* __restrict__ x,
                                                const float* __restrict__ Wp,
                                                const float* __restrict__ bp,
                                                const float* __restrict__ ws,
                                                float* __restrict__ out) {
    __shared__ float sRec[256][8];
    __shared__ float sLat[768];

    const int t = threadIdx.x;
    const int b = blockIdx.x * 256 + t;

    const float* xp = x + (size_t)b * 6;
    float2 x01 = *(const float2*)(xp);
    float2 x23 = *(const float2*)(xp + 2);
    float2 x45 = *(const float2*)(xp + 4);
    float xv[6] = {x01.x, x01.y, x23.x, x23.y, x45.x, x45.y};

    // h = tanh(x W^T + b) -> real initial state; S = ||h||^2
    float sr[64], si[64];
    float S = 0.0f;
#pragma unroll
    for (int i = 0; i < 64; ++i) {
        float a = bp[i];                    // uniform -> s_load
#pragma unroll
        for (int d = 0; d < 6; ++d) a += Wp[i * 6 + d] * xv[d];  // uniform -> s_load
        float th = fast_tanh(a);
        sr[i] = th;
        si[i] = 0.0f;
        S += th * th;
    }
    float invS = __builtin_amdgcn_rcpf(S);

    // encoder circuit in registers
#pragma unroll 1
    for (int bb = 0; bb < 3; ++bb) {
        const float* rx = ws + 64 + 12 * bb;  // uniform -> s_load
        apply_rx<5>(sr, si, rx[0], rx[1]);
        apply_rx<4>(sr, si, rx[2], rx[3]);
        apply_rx<3>(sr, si, rx[4], rx[5]);
        apply_rx<2>(sr, si, rx[6], rx[7]);
        apply_rx<1>(sr, si, rx[8], rx[9]);
        apply_rx<0>(sr, si, rx[10], rx[11]);
        const float* dg = ws + 128 + 128 * bb;  // uniform -> s_load
#pragma unroll
        for (int r = 0; r < 64; ++r) {
            float dr = dg[2 * r], di = dg[2 * r + 1];
            float ar = sr[r], ai = si[r];
            sr[r] = dr * ar - di * ai;
            si[r] = dr * ai + di * ar;
        }
    }

    // probs -> latent (Z expvals on qubits 0..2; qubit k = bit (5-k))
    float l0 = 0.0f, l1 = 0.0f, l2 = 0.0f;
#pragma unroll
    for (int j = 0; j < 64; ++j) {
        float p = sr[j] * sr[j] + si[j] * si[j];
        l0 += (j & 32) ? -p : p;
        l1 += (j & 16) ? -p : p;
        l2 += (j & 8) ? -p : p;
    }
    l0 *= invS; l1 *= invS; l2 *= invS;

    // decoder collapsed: recon_k = (l^T A_k l) / (l^T l)
    float r2 = l0 * l0 + l1 * l1 + l2 * l2;
    float invr2 = __builtin_amdgcn_rcpf(r2);
    float lv[3] = {l0, l1, l2};
    float rec[6];
#pragma unroll
    for (int k = 0; k < 6; ++k) {
        float acc = 0.0f;
#pragma unroll
        for (int d = 0; d < 3; ++d)
#pragma unroll
            for (int e = 0; e < 3; ++e) acc += ws[k * 9 + d * 3 + e] * lv[d] * lv[e];
        rec[k] = acc * invr2;
    }

    // stage for coalesced output
    sLat[t * 3 + 0] = l0;
    sLat[t * 3 + 1] = l1;
    sLat[t * 3 + 2] = l2;
#pragma unroll
    for (int d = 0; d < 6; ++d) sRec[t][d] = rec[d];
    __syncthreads();

    // latent out: fully coalesced
#pragma unroll
    for (int f = 0; f < 3; ++f)
        out[(size_t)BATCH * 64 + (size_t)blockIdx.x * 768 + f * 256 + t] = sLat[f * 256 + t];

    // recon out: each wave writes one batch element's 64 contiguous floats/iter
    const int i = t & 63;
    float wv[6];
#pragma unroll
    for (int d = 0; d < 6; ++d) wv[d] = Wp[i * 6 + d];
    float bi_ = bp[i];
    const size_t obase = (size_t)blockIdx.x * 256 * 64;
#pragma unroll 2
    for (int c = 0; c < 64; ++c) {
        int lb = c * 4 + (t >> 6);          // wave-uniform local batch index
        float4 ra = *(const float4*)&sRec[lb][0];   // LDS broadcast
        float2 rb = *(const float2*)&sRec[lb][4];
        float a = bi_ + wv[0] * ra.x + wv[1] * ra.y + wv[2] * ra.z +
                  wv[3] * ra.w + wv[4] * rb.x + wv[5] * rb.y;
        out[obase + (size_t)lb * 64 + i] = fast_tanh(a);
    }
}

extern "C" void kernel_launch(void* const* d_in, const int* in_sizes, int n_in,
                              void* d_out, int out_size, void* d_ws, size_t ws_size,
                              hipStream_t stream) {
    const float* x   = (const float*)d_in[0];
    const float* Wp  = (const float*)d_in[1];
    const float* bpv = (const float*)d_in[2];
    const float* enc = (const float*)d_in[3];
    const float* dec = (const float*)d_in[4];
    float* out = (float*)d_out;
    float* ws  = (float*)d_ws;

    prep_kernel<<<1, 256, 0, stream>>>(enc, dec, ws);
    qae_main<<<BATCH / 256, 256, 0, stream>>>(x, Wp, bpv, ws, out);
}

// Round 3
// 118.538 us; speedup vs baseline: 1.4113x; 1.0916x over previous
//
#include <hip/hip_runtime.h>

#define BATCH 131072

// ws layout (floats):
//  [0..53]     A: 6 matrices 3x3 (decoder collapsed: recon_k = (l^T A_k l)/(l^T l))
//  [64..99]    enc RX coeffs: gate g=bb*6+w -> ws[64+2g]=cos(tx/2), ws[65+2g]=sin(tx/2)
//  [128..511]  enc diag per block bb: ws[128+128*bb+2r]=Re D_r, +1=Im D_r

__device__ __forceinline__ float fast_tanh(float v) {
    float e = __expf(2.0f * v);
    return 1.0f - 2.0f / (e + 1.0f);
}

template <int CTRL>
__device__ __forceinline__ float dppf(float v) {
    return __int_as_float(__builtin_amdgcn_update_dpp(
        0, __float_as_int(v), CTRL, 0xF, 0xF, true));
}
#define DPP_XOR1 0xB1  // quad_perm [1,0,3,2]
#define DPP_XOR2 0x4E  // quad_perm [2,3,0,1]

// ---------------------------------------------------------------------------
// prep: (single block) decoder collapsed quadratic forms + encoder gate params
// ---------------------------------------------------------------------------
__global__ __launch_bounds__(256) void prep_kernel(const float* __restrict__ enc_w,
                                                   const float* __restrict__ dec_w,
                                                   float* __restrict__ ws) {
    __shared__ float gt[18][8];
    __shared__ float Sr[64][8];
    __shared__ float Si[64][8];
    const int t = threadIdx.x;

    if (t < 18) {
        float tx = dec_w[t * 3 + 0];
        float tz = dec_w[t * 3 + 1];
        float c = cosf(0.5f * tx), s = sinf(0.5f * tx);
        float ch = cosf(0.5f * tz), sh = sinf(0.5f * tz);
        gt[t][0] = c * ch;  gt[t][1] = -c * sh;
        gt[t][2] = -s * sh; gt[t][3] = -s * ch;
        gt[t][4] = s * sh;  gt[t][5] = -s * ch;
        gt[t][6] = c * ch;  gt[t][7] = c * sh;
    }

    const int cl = t & 7;
    const int pr = t >> 3;
    float* fSr = &Sr[0][0];
    float* fSi = &Si[0][0];
    for (int f = t; f < 512; f += 256) {
        int r = f >> 3, c = f & 7;
        fSr[f] = (r == c && c < 3) ? 1.0f : 0.0f;
        fSi[f] = 0.0f;
    }

    for (int bb = 0; bb < 3; ++bb) {
        for (int w = 0; w < 6; ++w) {
            __syncthreads();
            int g = bb * 6 + w;
            int p = 5 - w;
            float u00r = gt[g][0], u00i = gt[g][1], u01r = gt[g][2], u01i = gt[g][3];
            float u10r = gt[g][4], u10i = gt[g][5], u11r = gt[g][6], u11i = gt[g][7];
            int r0 = ((pr >> p) << (p + 1)) | (pr & ((1 << p) - 1));
            int r1 = r0 | (1 << p);
            float ar = Sr[r0][cl], ai = Si[r0][cl];
            float br = Sr[r1][cl], bi = Si[r1][cl];
            Sr[r0][cl] = u00r * ar - u00i * ai + u01r * br - u01i * bi;
            Si[r0][cl] = u00r * ai + u00i * ar + u01r * bi + u01i * br;
            Sr[r1][cl] = u10r * ar - u10i * ai + u11r * br - u11i * bi;
            Si[r1][cl] = u10r * ai + u10i * ar + u11r * bi + u11i * br;
        }
        __syncthreads();
        for (int f = t; f < 512; f += 256) {
            int r = f >> 3;
            if (__popc(r & (r >> 1)) & 1) {
                fSr[f] = -fSr[f];
                fSi[f] = -fSi[f];
            }
        }
    }
    __syncthreads();

    if (t < 54) {
        int k = t / 9, d = (t % 9) / 3, e = t % 3;
        float acc = 0.0f;
        for (int r = 0; r < 64; ++r) {
            float term = Sr[r][d] * Sr[r][e] + Si[r][d] * Si[r][e];
            acc += ((r >> (5 - k)) & 1) ? -term : term;
        }
        ws[t] = acc;
    }

    if (t < 18) {
        float tx = enc_w[t * 3 + 0];
        ws[64 + 2 * t] = cosf(0.5f * tx);
        ws[65 + 2 * t] = sinf(0.5f * tx);
    }

    if (t >= 64 && t < 256) {
        int idx = t - 64;
        int bb = idx >> 6, r = idx & 63;
        float phi = 0.0f;
        for (int k = 0; k < 6; ++k) {
            float tz = enc_w[(bb * 6 + k) * 3 + 1];
            phi += ((r >> (5 - k)) & 1) ? 0.5f * tz : -0.5f * tz;
        }
        float sgn = (__popc(r & (r >> 1)) & 1) ? -1.0f : 1.0f;
        ws[128 + bb * 128 + 2 * r] = sgn * cosf(phi);
        ws[129 + bb * 128 + 2 * r] = sgn * sinf(phi);
    }
}

// ---------------------------------------------------------------------------
// RX butterfly on local bit Q of m (amplitude bit Q+2)
// ---------------------------------------------------------------------------
template <int Q>
__device__ __forceinline__ void rx_local(float* sr, float* si, float c, float s) {
#pragma unroll
    for (int k = 0; k < 8; ++k) {
        int lo = k & ((1 << Q) - 1);
        int m0 = ((k >> Q) << (Q + 1)) | lo;
        int m1 = m0 | (1 << Q);
        float ar = sr[m0], ai = si[m0], br = sr[m1], bi = si[m1];
        sr[m0] = c * ar + s * bi;
        si[m0] = c * ai - s * br;
        sr[m1] = c * br + s * ai;
        si[m1] = c * bi - s * ar;
    }
}

// cross-lane RX butterfly; both sides use identical update (RX symmetry):
// new = (c*mr + s*pi, c*mi - s*pr) where (pr,pi) is the partner amplitude.
template <int CTRL>
__device__ __forceinline__ void rx_exch(float* sr, float* si, float c, float s) {
#pragma unroll
    for (int m = 0; m < 16; ++m) {
        float pr = dppf<CTRL>(sr[m]);
        float pi = dppf<CTRL>(si[m]);
        float mr = sr[m], mi = si[m];
        sr[m] = c * mr + s * pi;
        si[m] = c * mi - s * pr;
    }
}

// ---------------------------------------------------------------------------
// main: 4 threads per batch element (sub = t&3 = amplitude bits [1:0]);
// each thread holds 16 complex amplitudes r = 4m + sub in registers.
// ---------------------------------------------------------------------------
__global__ __launch_bounds__(256, 4) void qae_main(const float* __restrict__ x,
                                                   const float* __restrict__ Wp,
                                                   const float* __restrict__ bp,
                                                   const float* __restrict__ ws,
                                                   float* __restrict__ out) {
    __shared__ float sW[512];   // row i: W[i][0..5], b[i], pad
    __shared__ float sD[384];   // 3 blocks x 64 x {re,im}
    __shared__ float sLat[192];

    const int t = threadIdx.x;
    const int bl = t >> 2;      // local batch element 0..63
    const int sub = t & 3;      // amplitude low bits

    for (int f = t; f < 512; f += 256) {
        int i = f >> 3, c = f & 7;
        sW[f] = (c < 6) ? Wp[i * 6 + c] : ((c == 6) ? bp[i] : 0.0f);
    }
    for (int f = t; f < 384; f += 256) sD[f] = ws[128 + f];
    __syncthreads();

    const size_t b = (size_t)blockIdx.x * 64 + bl;
    const float* xp = x + b * 6;
    float2 x01 = *(const float2*)(xp);
    float2 x23 = *(const float2*)(xp + 2);
    float2 x45 = *(const float2*)(xp + 4);
    float xv[6] = {x01.x, x01.y, x23.x, x23.y, x45.x, x45.y};

    // h rows r = 4m+sub ; S = ||h||^2 reduced over quad
    float sr[16], si[16];
    float S = 0.0f;
    const float* wbase = &sW[sub * 8];
#pragma unroll
    for (int m = 0; m < 16; ++m) {
        const float* wr = wbase + m * 32;
        float4 w0 = *(const float4*)wr;
        float4 w1 = *(const float4*)(wr + 4);
        float a = w1.z + w0.x * xv[0] + w0.y * xv[1] + w0.z * xv[2] +
                  w0.w * xv[3] + w1.x * xv[4] + w1.y * xv[5];
        float th = fast_tanh(a);
        sr[m] = th;
        si[m] = 0.0f;
        S += th * th;
    }
    S += dppf<DPP_XOR1>(S);
    S += dppf<DPP_XOR2>(S);
    float invS = __builtin_amdgcn_rcpf(S);

    // encoder circuit: wires 0..3 local (m bits 3..0), wires 4,5 cross-lane
#pragma unroll 1
    for (int bb = 0; bb < 3; ++bb) {
        const float* rx = ws + 64 + 12 * bb;   // uniform -> s_load
        rx_local<3>(sr, si, rx[0], rx[1]);
        rx_local<2>(sr, si, rx[2], rx[3]);
        rx_local<1>(sr, si, rx[4], rx[5]);
        rx_local<0>(sr, si, rx[6], rx[7]);
        rx_exch<DPP_XOR2>(sr, si, rx[8], rx[9]);    // wire 4: r bit1 = lane bit1
        rx_exch<DPP_XOR1>(sr, si, rx[10], rx[11]);  // wire 5: r bit0 = lane bit0
        const float* dgl = &sD[bb * 128 + sub * 2];
#pragma unroll
        for (int m = 0; m < 16; ++m) {
            float2 d = *(const float2*)&dgl[8 * m];
            float ar = sr[m], ai = si[m];
            sr[m] = d.x * ar - d.y * ai;
            si[m] = d.x * ai + d.y * ar;
        }
    }

    // latent: signs from r bits 5,4,3 = m bits 3,2,1 (compile-time)
    float l0 = 0.0f, l1 = 0.0f, l2 = 0.0f;
#pragma unroll
    for (int m = 0; m < 16; ++m) {
        float p = sr[m] * sr[m] + si[m] * si[m];
        l0 += (m & 8) ? -p : p;
        l1 += (m & 4) ? -p : p;
        l2 += (m & 2) ? -p : p;
    }
    l0 += dppf<DPP_XOR1>(l0); l0 += dppf<DPP_XOR2>(l0);
    l1 += dppf<DPP_XOR1>(l1); l1 += dppf<DPP_XOR2>(l1);
    l2 += dppf<DPP_XOR1>(l2); l2 += dppf<DPP_XOR2>(l2);
    l0 *= invS; l1 *= invS; l2 *= invS;

    // decoder collapsed: recon_k = (l^T A_k l) / (l^T l)  (A uniform -> s_load)
    float r2 = l0 * l0 + l1 * l1 + l2 * l2;
    float invr2 = __builtin_amdgcn_rcpf(r2);
    float lv[3] = {l0, l1, l2};
    float rec[6];
#pragma unroll
    for (int k = 0; k < 6; ++k) {
        float acc = 0.0f;
#pragma unroll
        for (int d = 0; d < 3; ++d)
#pragma unroll
            for (int e = 0; e < 3; ++e) acc += ws[k * 9 + d * 3 + e] * lv[d] * lv[e];
        rec[k] = acc * invr2;
    }

    // latent out (staged for coalescing)
    if (sub == 0) {
        sLat[bl * 3 + 0] = l0;
        sLat[bl * 3 + 1] = l1;
        sLat[bl * 3 + 2] = l2;
    }
    __syncthreads();
    if (t < 192) out[(size_t)BATCH * 64 + (size_t)blockIdx.x * 192 + t] = sLat[t];

    // reconstructed = tanh(rec W^T + b): thread writes rows 16*sub..16*sub+15
    const size_t ob = b * 64 + sub * 16;
#pragma unroll
    for (int q = 0; q < 4; ++q) {
        float vals[4];
#pragma unroll
        for (int c2 = 0; c2 < 4; ++c2) {
            const float* wr = &sW[(sub * 16 + q * 4 + c2) * 8];
            float4 w0 = *(const float4*)wr;
            float4 w1 = *(const float4*)(wr + 4);
            float a = w1.z + w0.x * rec[0] + w0.y * rec[1] + w0.z * rec[2] +
                      w0.w * rec[3] + w1.x * rec[4] + w1.y * rec[5];
            vals[c2] = fast_tanh(a);
        }
        float4 o = {vals[0], vals[1], vals[2], vals[3]};
        *(float4*)&out[ob + q * 4] = o;
    }
}

extern "C" void kernel_launch(void* const* d_in, const int* in_sizes, int n_in,
                              void* d_out, int out_size, void* d_ws, size_t ws_size,
                              hipStream_t stream) {
    const float* x   = (const float*)d_in[0];
    const float* Wp  = (const float*)d_in[1];
    const float* bpv = (const float*)d_in[2];
    const float* enc = (const float*)d_in[3];
    const float* dec = (const float*)d_in[4];
    float* out = (float*)d_out;
    float* ws  = (float*)d_ws;

    prep_kernel<<<1, 256, 0, stream>>>(enc, dec, ws);
    qae_main<<<(BATCH * 4) / 256, 256, 0, stream>>>(x, Wp, bpv, ws, out);
}

// Round 4
// 105.425 us; speedup vs baseline: 1.5868x; 1.1244x over previous
//
#include <hip/hip_runtime.h>

#define BATCH 131072

typedef float v2f __attribute__((ext_vector_type(2)));

// ws layout (floats):
//  [0..53]     A: 6 matrices 3x3 (decoder collapsed: recon_k = (l^T A_k l)/(l^T l))
//  [64..99]    enc RX coeffs: gate g=bb*6+w -> ws[64+2g]=cos(tx/2), ws[65+2g]=sin(tx/2)
//  [128..511]  enc diag per block bb: ws[128+128*bb+2r]=Re D_r, +1=Im D_r

__device__ __forceinline__ float fast_tanh(float v) {
    float e = __expf(2.0f * v);
    return 1.0f - 2.0f / (e + 1.0f);
}

template <int CTRL>
__device__ __forceinline__ float dppf(float v) {
    return __int_as_float(__builtin_amdgcn_update_dpp(
        0, __float_as_int(v), CTRL, 0xF, 0xF, true));
}
#define DPP_XOR1 0xB1  // quad_perm [1,0,3,2]
#define DPP_XOR2 0x4E  // quad_perm [2,3,0,1]

__device__ __forceinline__ v2f swap2(v2f v) { return __builtin_shufflevector(v, v, 1, 0); }

// ---------------------------------------------------------------------------
// prep (unchanged from round 3)
// ---------------------------------------------------------------------------
__global__ __launch_bounds__(256) void prep_kernel(const float* __restrict__ enc_w,
                                                   const float* __restrict__ dec_w,
                                                   float* __restrict__ ws) {
    __shared__ float gt[18][8];
    __shared__ float Sr[64][8];
    __shared__ float Si[64][8];
    const int t = threadIdx.x;

    if (t < 18) {
        float tx = dec_w[t * 3 + 0];
        float tz = dec_w[t * 3 + 1];
        float c = cosf(0.5f * tx), s = sinf(0.5f * tx);
        float ch = cosf(0.5f * tz), sh = sinf(0.5f * tz);
        gt[t][0] = c * ch;  gt[t][1] = -c * sh;
        gt[t][2] = -s * sh; gt[t][3] = -s * ch;
        gt[t][4] = s * sh;  gt[t][5] = -s * ch;
        gt[t][6] = c * ch;  gt[t][7] = c * sh;
    }

    const int cl = t & 7;
    const int pr = t >> 3;
    float* fSr = &Sr[0][0];
    float* fSi = &Si[0][0];
    for (int f = t; f < 512; f += 256) {
        int r = f >> 3, c = f & 7;
        fSr[f] = (r == c && c < 3) ? 1.0f : 0.0f;
        fSi[f] = 0.0f;
    }

    for (int bb = 0; bb < 3; ++bb) {
        for (int w = 0; w < 6; ++w) {
            __syncthreads();
            int g = bb * 6 + w;
            int p = 5 - w;
            float u00r = gt[g][0], u00i = gt[g][1], u01r = gt[g][2], u01i = gt[g][3];
            float u10r = gt[g][4], u10i = gt[g][5], u11r = gt[g][6], u11i = gt[g][7];
            int r0 = ((pr >> p) << (p + 1)) | (pr & ((1 << p) - 1));
            int r1 = r0 | (1 << p);
            float ar = Sr[r0][cl], ai = Si[r0][cl];
            float br = Sr[r1][cl], bi = Si[r1][cl];
            Sr[r0][cl] = u00r * ar - u00i * ai + u01r * br - u01i * bi;
            Si[r0][cl] = u00r * ai + u00i * ar + u01r * bi + u01i * br;
            Sr[r1][cl] = u10r * ar - u10i * ai + u11r * br - u11i * bi;
            Si[r1][cl] = u10r * ai + u10i * ar + u11r * bi + u11i * br;
        }
        __syncthreads();
        for (int f = t; f < 512; f += 256) {
            int r = f >> 3;
            if (__popc(r & (r >> 1)) & 1) {
                fSr[f] = -fSr[f];
                fSi[f] = -fSi[f];
            }
        }
    }
    __syncthreads();

    if (t < 54) {
        int k = t / 9, d = (t % 9) / 3, e = t % 3;
        float acc = 0.0f;
        for (int r = 0; r < 64; ++r) {
            float term = Sr[r][d] * Sr[r][e] + Si[r][d] * Si[r][e];
            acc += ((r >> (5 - k)) & 1) ? -term : term;
        }
        ws[t] = acc;
    }

    if (t < 18) {
        float tx = enc_w[t * 3 + 0];
        ws[64 + 2 * t] = cosf(0.5f * tx);
        ws[65 + 2 * t] = sinf(0.5f * tx);
    }

    if (t >= 64 && t < 256) {
        int idx = t - 64;
        int bb = idx >> 6, r = idx & 63;
        float phi = 0.0f;
        for (int k = 0; k < 6; ++k) {
            float tz = enc_w[(bb * 6 + k) * 3 + 1];
            phi += ((r >> (5 - k)) & 1) ? 0.5f * tz : -0.5f * tz;
        }
        float sgn = (__popc(r & (r >> 1)) & 1) ? -1.0f : 1.0f;
        ws[128 + bb * 128 + 2 * r] = sgn * cosf(phi);
        ws[129 + bb * 128 + 2 * r] = sgn * sinf(phi);
    }
}

// ---------------------------------------------------------------------------
// Packed butterflies. State: v2f packs P[j] = (amp(m=2j), amp(m=2j+1)),
// amplitude r = 4m + sub, sub = lane&3.
// ---------------------------------------------------------------------------
template <int MASK>  // pack-to-pack RX (wires 0..2: j bits 2,1,0)
__device__ __forceinline__ void rx_pairs(v2f* zr, v2f* zi, float c, float s) {
#pragma unroll
    for (int j = 0; j < 8; ++j) {
        if (j & MASK) continue;
        int j1 = j | MASK;
        v2f ar = zr[j], ai = zi[j], br = zr[j1], bi = zi[j1];
        zr[j]  = c * ar + s * bi;
        zi[j]  = c * ai - s * br;
        zr[j1] = c * br + s * ai;
        zi[j1] = c * bi - s * ar;
    }
}

template <int CTRL>  // cross-lane RX (wires 4,5: lane bits)
__device__ __forceinline__ void rx_exch2(v2f* zr, v2f* zi, float c, float s) {
#pragma unroll
    for (int j = 0; j < 8; ++j) {
        v2f pr, pi;
        pr.x = dppf<CTRL>(zr[j].x);
        pr.y = dppf<CTRL>(zr[j].y);
        pi.x = dppf<CTRL>(zi[j].x);
        pi.y = dppf<CTRL>(zi[j].y);
        v2f mr = zr[j], mi = zi[j];
        zr[j] = c * mr + s * pi;
        zi[j] = c * mi - s * pr;
    }
}

// ---------------------------------------------------------------------------
// main: 4 threads/batch element; 8 v2f packs per thread.
// sW layout: group g = j*4+su holds rows (8j+su, 8j+4+su) interleaved:
//   phys(g,e) = g*16 + (g>>2)*4 + e ; e = 2d+half for W, 12+half bias, 14 pad
// Bank math: h-phase lanes differ by su*16+4j -> 2-way (free);
// epilogue lanes differ by 8*sub -> conflict-free.
// ---------------------------------------------------------------------------
__global__ __launch_bounds__(256) void qae_main(const float* __restrict__ x,
                                                const float* __restrict__ Wp,
                                                const float* __restrict__ bp,
                                                const float* __restrict__ ws,
                                                float* __restrict__ out) {
    __shared__ float sW[540];
    __shared__ float sD[256];   // blocks 0,1: ((bb*8+j)*4+su)*4 = (DrLo,DrHi,DiLo,DiHi)
    __shared__ float sLat[192];

    const int t = threadIdx.x;
    const int bl = t >> 2;
    const int sub = t & 3;

    for (int f = t; f < 512; f += 256) {
        int g = f >> 4, e = f & 15;
        int j = g >> 2, su = g & 3;
        float val;
        if (e < 12)      { int row = 8 * j + su + 4 * (e & 1); val = Wp[row * 6 + (e >> 1)]; }
        else if (e < 14) { int row = 8 * j + su + 4 * (e - 12); val = bp[row]; }
        else val = 0.0f;
        sW[g * 16 + j * 4 + e] = val;
    }
    if (t < 128) {
        int bb = t >> 6, r = t & 63;
        int su = r & 3, m = r >> 2, j = m >> 1, hm = m & 1;
        int base = ((bb * 8 + j) * 4 + su) * 4;
        sD[base + hm]     = ws[128 + bb * 128 + 2 * r];
        sD[base + 2 + hm] = ws[128 + bb * 128 + 2 * r + 1];
    }
    __syncthreads();

    const size_t b = (size_t)blockIdx.x * 64 + bl;
    const float* xp = x + b * 6;
    float2 x01 = *(const float2*)(xp);
    float2 x23 = *(const float2*)(xp + 2);
    float2 x45 = *(const float2*)(xp + 4);
    float xv[6] = {x01.x, x01.y, x23.x, x23.y, x45.x, x45.y};

    // h = tanh(xW^T+b): pack j holds rows (8j+sub, 8j+4+sub)
    v2f zr[8], zi[8];
    v2f S2 = {0.0f, 0.0f};
#pragma unroll
    for (int j = 0; j < 8; ++j) {
        const float* wb = &sW[(j * 4 + sub) * 16 + j * 4];
        float4 c0 = *(const float4*)wb;
        float4 c1 = *(const float4*)(wb + 4);
        float4 c2 = *(const float4*)(wb + 8);
        float4 c3 = *(const float4*)(wb + 12);
        v2f a = {c3.x, c3.y};
        a += xv[0] * (v2f){c0.x, c0.y};
        a += xv[1] * (v2f){c0.z, c0.w};
        a += xv[2] * (v2f){c1.x, c1.y};
        a += xv[3] * (v2f){c1.z, c1.w};
        a += xv[4] * (v2f){c2.x, c2.y};
        a += xv[5] * (v2f){c2.z, c2.w};
        v2f th = {fast_tanh(a.x), fast_tanh(a.y)};
        zr[j] = th;
        zi[j] = (v2f){0.0f, 0.0f};
        S2 += th * th;
    }
    float S = S2.x + S2.y;
    S += dppf<DPP_XOR1>(S);
    S += dppf<DPP_XOR2>(S);
    float invS = __builtin_amdgcn_rcpf(S);

    // encoder circuit (RX's within a block commute; diag of last block dropped: |D|=1)
#pragma unroll 1
    for (int bb = 0; bb < 3; ++bb) {
        const float* rx = ws + 64 + 12 * bb;   // uniform -> s_load
        rx_pairs<4>(zr, zi, rx[0], rx[1]);     // wire 0: r bit5 = j bit2
        rx_pairs<2>(zr, zi, rx[2], rx[3]);     // wire 1: r bit4 = j bit1
        rx_pairs<1>(zr, zi, rx[4], rx[5]);     // wire 2: r bit3 = j bit0
        {                                       // wire 3: r bit2 = pack half
            float c = rx[6], s = rx[7];
#pragma unroll
            for (int j = 0; j < 8; ++j) {
                v2f orr = zr[j], oi = zi[j];
                zr[j] = c * orr + s * swap2(oi);
                zi[j] = c * oi - s * swap2(orr);
            }
        }
        rx_exch2<DPP_XOR2>(zr, zi, rx[8], rx[9]);    // wire 4: lane bit1
        rx_exch2<DPP_XOR1>(zr, zi, rx[10], rx[11]);  // wire 5: lane bit0
        if (bb < 2) {
#pragma unroll
            for (int j = 0; j < 8; ++j) {
                float4 d = *(const float4*)&sD[((bb * 8 + j) * 4 + sub) * 4];
                v2f dr = {d.x, d.y}, di = {d.z, d.w};
                v2f orr = zr[j], oi = zi[j];
                zr[j] = dr * orr - di * oi;
                zi[j] = dr * oi + di * orr;
            }
        }
    }

    // latent: signs from r bits 5,4,3 = j bits 2,1,0 (same for both pack halves)
    v2f L0 = {0, 0}, L1 = {0, 0}, L2 = {0, 0};
#pragma unroll
    for (int j = 0; j < 8; ++j) {
        v2f p = zr[j] * zr[j] + zi[j] * zi[j];
        L0 += (j & 4) ? -p : p;
        L1 += (j & 2) ? -p : p;
        L2 += (j & 1) ? -p : p;
    }
    float l0 = L0.x + L0.y, l1 = L1.x + L1.y, l2 = L2.x + L2.y;
    l0 += dppf<DPP_XOR1>(l0); l0 += dppf<DPP_XOR2>(l0);
    l1 += dppf<DPP_XOR1>(l1); l1 += dppf<DPP_XOR2>(l1);
    l2 += dppf<DPP_XOR1>(l2); l2 += dppf<DPP_XOR2>(l2);
    l0 *= invS; l1 *= invS; l2 *= invS;

    // decoder collapsed: recon_k = (l^T A_k l)/(l^T l)  (A uniform -> s_load)
    float r2 = l0 * l0 + l1 * l1 + l2 * l2;
    float invr2 = __builtin_amdgcn_rcpf(r2);
    float lv[3] = {l0, l1, l2};
    float rec[6];
#pragma unroll
    for (int k = 0; k < 6; ++k) {
        float acc = 0.0f;
#pragma unroll
        for (int d = 0; d < 3; ++d)
#pragma unroll
            for (int e = 0; e < 3; ++e) acc += ws[k * 9 + d * 3 + e] * lv[d] * lv[e];
        rec[k] = acc * invr2;
    }

    // latent out
    if (sub == 0) {
        sLat[bl * 3 + 0] = l0;
        sLat[bl * 3 + 1] = l1;
        sLat[bl * 3 + 2] = l2;
    }
    __syncthreads();
    if (t < 192) out[(size_t)BATCH * 64 + (size_t)blockIdx.x * 192 + t] = sLat[t];

    // reconstructed = tanh(rec W^T + b); thread covers rows 16*sub..16*sub+15
    const size_t ob = b * 64;
#pragma unroll
    for (int jj = 0; jj < 2; ++jj) {
        int jrow = 2 * sub + jj;
        float vlo[4], vhi[4];
#pragma unroll
        for (int su2 = 0; su2 < 4; ++su2) {
            int g = jrow * 4 + su2;
            const float* wb = &sW[g * 16 + jrow * 4];
            float4 c0 = *(const float4*)wb;
            float4 c1 = *(const float4*)(wb + 4);
            float4 c2 = *(const float4*)(wb + 8);
            float2 b2 = *(const float2*)(wb + 12);
            v2f a = {b2.x, b2.y};
            a += rec[0] * (v2f){c0.x, c0.y};
            a += rec[1] * (v2f){c0.z, c0.w};
            a += rec[2] * (v2f){c1.x, c1.y};
            a += rec[3] * (v2f){c1.z, c1.w};
            a += rec[4] * (v2f){c2.x, c2.y};
            a += rec[5] * (v2f){c2.z, c2.w};
            vlo[su2] = fast_tanh(a.x);   // row 8*jrow + su2
            vhi[su2] = fast_tanh(a.y);   // row 8*jrow + 4 + su2
        }
        float4 o0 = {vlo[0], vlo[1], vlo[2], vlo[3]};
        float4 o1 = {vhi[0], vhi[1], vhi[2], vhi[3]};
        *(float4*)&out[ob + 8 * jrow]     = o0;
        *(float4*)&out[ob + 8 * jrow + 4] = o1;
    }
}

extern "C" void kernel_launch(void* const* d_in, const int* in_sizes, int n_in,
                              void* d_out, int out_size, void* d_ws, size_t ws_size,
                              hipStream_t stream) {
    const float* x   = (const float*)d_in[0];
    const float* Wp  = (const float*)d_in[1];
    const float* bpv = (const float*)d_in[2];
    const float* enc = (const float*)d_in[3];
    const float* dec = (const float*)d_in[4];
    float* out = (float*)d_out;
    float* ws  = (float*)d_ws;

    prep_kernel<<<1, 256, 0, stream>>>(enc, dec, ws);
    qae_main<<<(BATCH * 4) / 256, 256, 0, stream>>>(x, Wp, bpv, ws, out);
}